// Round 11
// baseline (168.136 us; speedup 1.0000x reference)
//
#include <hip/hip_runtime.h>
#include <math.h>

// GAT aggregation: B=8,S=512,N=32,H=256,V=100001
// One WAVE per position, ALL 4096 waves co-resident (16 waves/CU at
// launch_bounds(256,6) -> 24 resident capacity). Masked neighbors have
// softmax weight exactly +0 (exp(-1e9-m) underflows) and are never loaded.
// Round-11 structure (max positions-in-flight x short chain):
//  - phase 1: each surviving row is loaded, FMA'd into a per-candidate
//    partial red[c], and DISCARDED (no float4 ring -> ~65 VGPR, no spills).
//    All ~17 loads independent and in flight together.
//  - one batched butterfly reduces all partials (independent trees, no
//    serial rescale chain).
//  - phase 2: softmax over known logits, rows RELOADED (L2-hot) for the
//    weighted accumulate.
//  - zero LDS, zero barriers, no merge. Candidate ids/mask live lane-
//    parallel; per-candidate scalarization via v_readlane (literal lane).

constexpr int H  = 256;
constexpr int NN = 32;        // neighbors
constexpr int C  = NN + 1;    // candidates: self + neighbors
constexpr float SLOPE = 0.2f;

__global__ __launch_bounds__(256, 6) void gat_kernel(
    const int*   __restrict__ node_ids,   // [npos]
    const int*   __restrict__ neighs,     // [npos, NN]
    const int*   __restrict__ mask,       // [npos, NN]
    const float* __restrict__ emb,        // [V, H]
    const float* __restrict__ a_w,        // [2H]
    const float* __restrict__ a_b,        // [1]
    float*       __restrict__ out,        // [npos, H]
    int npos)
{
  const int wid  = (blockIdx.x * blockDim.x + threadIdx.x) >> 6;
  const int lane = threadIdx.x & 63;
  if (wid >= npos) return;
  const int l4 = lane << 2;

  const float4 aw1 = *(const float4*)(a_w + l4);        // src half of a_w
  const float4 aw2 = *(const float4*)(a_w + H + l4);    // candidate half
  const float  ab  = a_b[0];

  // Lane-parallel ids/mask: lane 0 = self (never masked), 1..NN = neighbors.
  int my_idx = 0, my_mact = 1;
  if (lane == 0) {
    my_idx  = node_ids[wid];
    my_mact = 0;
  } else if (lane <= NN) {
    my_idx  = neighs[wid * NN + lane - 1];
    my_mact = mask[wid * NN + lane - 1];
  }

  const float4* __restrict__ embv = (const float4*)emb; // row = H/4 float4

  // ---- phase 1: load rows once, fold into per-candidate dot partials ----
  float red[C];
  float zp;                                             // src.aw1 partial
  {
    const int i0 = __builtin_amdgcn_readlane(my_idx, 0);
    const float4 e0 = embv[(size_t)i0 * (H / 4) + lane];
    zp     = e0.x * aw1.x + e0.y * aw1.y + e0.z * aw1.z + e0.w * aw1.w;
    red[0] = e0.x * aw2.x + e0.y * aw2.y + e0.z * aw2.z + e0.w * aw2.w;
  }
#pragma unroll
  for (int c = 1; c < C; ++c) {
    const int mc = __builtin_amdgcn_readlane(my_mact, c);  // SGPR
    if (mc == 0) {                                         // uniform branch
      const int ic = __builtin_amdgcn_readlane(my_idx, c); // SGPR row index
      const float4 e = embv[(size_t)ic * (H / 4) + lane];
      red[c] = e.x * aw2.x + e.y * aw2.y + e.z * aw2.z + e.w * aw2.w;
    } else {
      red[c] = 0.f;                                        // masked: skipped
    }
  }

  // ---- batched butterflies (independent trees; masked slots skipped) ----
#pragma unroll
  for (int off = 32; off > 0; off >>= 1)
    zp += __shfl_xor(zp, off, 64);
#pragma unroll
  for (int c = 0; c < C; ++c) {
    const int mc = __builtin_amdgcn_readlane(my_mact, c);
    if (mc == 0) {
#pragma unroll
      for (int off = 32; off > 0; off >>= 1)
        red[c] += __shfl_xor(red[c], off, 64);
    }
  }

  // ---- softmax over surviving logits (wave-uniform values) ----
  float m = -1e30f;
#pragma unroll
  for (int c = 0; c < C; ++c) {
    const int mc = __builtin_amdgcn_readlane(my_mact, c);
    if (mc == 0) {
      const float z = zp + red[c] + ab;
      red[c] = (z > 0.f) ? z : SLOPE * z;                 // LeakyReLU(0.2)
      m = fmaxf(m, red[c]);
    }
  }
  float s = 0.f;
#pragma unroll
  for (int c = 0; c < C; ++c) {
    const int mc = __builtin_amdgcn_readlane(my_mact, c);
    if (mc == 0) {
      red[c] = __expf(red[c] - m);
      s += red[c];
    }
  }
  const float inv = 1.f / s;

  // ---- phase 2: reload rows (L2-hot) and accumulate ----
  float4 acc = {0.f, 0.f, 0.f, 0.f};
#pragma unroll
  for (int c = 0; c < C; ++c) {
    const int mc = __builtin_amdgcn_readlane(my_mact, c);
    if (mc == 0) {
      const int ic = __builtin_amdgcn_readlane(my_idx, c);
      const float4 e = embv[(size_t)ic * (H / 4) + lane];
      const float w = red[c] * inv;
      acc.x += w * e.x;
      acc.y += w * e.y;
      acc.z += w * e.z;
      acc.w += w * e.w;
    }
  }
  *(float4*)(out + (size_t)wid * H + l4) = acc;
}

extern "C" void kernel_launch(void* const* d_in, const int* in_sizes, int n_in,
                              void* d_out, int out_size, void* d_ws, size_t ws_size,
                              hipStream_t stream) {
  const int*   node_ids = (const int*)d_in[0];
  const int*   neighs   = (const int*)d_in[1];
  const int*   mask     = (const int*)d_in[2];
  const float* emb      = (const float*)d_in[3];
  const float* a_w      = (const float*)d_in[4];
  const float* a_b      = (const float*)d_in[5];
  float*       out      = (float*)d_out;

  const int npos = in_sizes[0];           // B*S = 4096
  const int waves_per_block = 256 / 64;   // 4 positions per block
  const int grid = (npos + waves_per_block - 1) / waves_per_block;

  gat_kernel<<<grid, 256, 0, stream>>>(node_ids, neighs, mask, emb, a_w, a_b,
                                       out, npos);
}